// Round 5
// baseline (230.935 us; speedup 1.0000x reference)
//
#include <hip/hip_runtime.h>

#define NSENT 4000
#define LSEQ  128
#define VEC   50
#define POS   5
#define EMBD  60      // VEC + 2*POS
#define HIDD  230
#define HSTR  232     // padded channel stride for H
#define NBAG  500
#define NREL  25
#define NTILEP 16     // padded N-tile count (15 real, tile 15 = zeros)
#define KSTEPS 6      // K = 192 (3 taps * 64 e-slots), 6 MFMA K-steps of 32
#define ESTR  72      // LDS row stride in bf16 shorts (144 B)
#define SLOTS 130     // l+1 shift; rows 0/129 are SAME-pad zeros

// e-slot mapping (A and B must agree): 0..49 wemb | 50..54 p1 | 55 zero
//                                      56..60 p2  | 61..63 zero
typedef __attribute__((ext_vector_type(8))) short short8;   // 8 bf16 = 4 VGPRs
typedef __attribute__((ext_vector_type(4))) float f32x4;

__device__ __forceinline__ unsigned short f2bf(float f) {
    union { float f; unsigned u; } v; v.f = f;
    unsigned u = v.u + 0x7FFF + ((v.u >> 16) & 1);   // RNE
    return (unsigned short)(u >> 16);
}

// ---- fused prep: [0,WBLK) wordtab | [WBLK,WBLK+PBLK) postab | rest transpose_w ----
#define WPAIRS 1250050           // 50002*50/2
#define WBLK   4883              // ceil(WPAIRS/256)
#define PBLK   10                // ceil(2*201*6/256)
#define TBLK   192               // NTILEP*KSTEPS*64*8/256
__global__ __launch_bounds__(256) void prep(const float* __restrict__ wemb,
                                            const float* __restrict__ p1emb,
                                            const float* __restrict__ p2emb,
                                            const float* __restrict__ conv_w,
                                            unsigned short* __restrict__ wembh,
                                            unsigned short* __restrict__ p1h,
                                            unsigned short* __restrict__ p2h,
                                            unsigned short* __restrict__ Bfrag,
                                            int base) {
    int blk = blockIdx.x + base;
    if (blk < WBLK) {
        int idx = blk * 256 + threadIdx.x;
        if (idx < WPAIRS) {
            float2 f = ((const float2*)wemb)[idx];
            union { unsigned short s[2]; unsigned u; } o;
            o.s[0] = f2bf(f.x); o.s[1] = f2bf(f.y);
            *(unsigned*)(wembh + idx * 2) = o.u;
        }
    } else if (blk < WBLK + PBLK) {
        int idx = (blk - WBLK) * 256 + threadIdx.x;
        if (idx < 2 * 201 * 6) {
            int t = idx >= 201 * 6;
            int rem = idx - t * 201 * 6;
            int row = rem / 6, col = rem - row * 6;
            const float* src = t ? p2emb : p1emb;
            unsigned short* dst = t ? p2h : p1h;
            dst[rem] = (col < POS) ? f2bf(src[row * POS + col]) : 0;
        }
    } else {
        int idx = (blk - WBLK - PBLK) * 256 + threadIdx.x;
        // B layout for mfma_f32_16x16x32_bf16: B[n = lane&15][k = (lane>>4)*8 + j]
        int j    = idx & 7;
        int lane = (idx >> 3) & 63;
        int t    = idx >> 9;
        int ks   = t % KSTEPS;
        int nt   = t / KSTEPS;
        int c    = nt * 16 + (lane & 15);
        int klin = ks * 32 + (lane >> 4) * 8 + j;
        int tap  = klin >> 6;
        int e    = klin & 63;
        float v  = 0.f;
        if (c < HIDD) {
            int eidx = -1;
            if (e < 55)                 eidx = e;       // wemb 0..49, p1 50..54
            else if (e >= 56 && e < 61) eidx = e - 1;   // p2 55..59
            if (eidx >= 0) v = conv_w[(c * EMBD + eidx) * 3 + tap];
        }
        Bfrag[idx] = f2bf(v);
    }
}

// ---- Kernel 2: gather + conv1d(k=3,SAME) via bf16 MFMA + maxpool + bias + relu ----
// one block = 256 thr = 4 waves per sentence; wave w owns N-tiles {4w..4w+3}
// B = 96 VGPRs/wave, branch-free (padded tiles) so liveness is unconditional.
// A-frag A[m=lane&15][k=quad*8+j] from LDS; C tile col=lane&15, row=quad*4+reg
template <bool TBL>
__global__ __launch_bounds__(256) void encoder(
    const int*   __restrict__ X,  const int* __restrict__ P1, const int* __restrict__ P2,
    const float* __restrict__ wemb, const float* __restrict__ p1emb, const float* __restrict__ p2emb,
    const unsigned short* __restrict__ wembh, const unsigned short* __restrict__ p1h,
    const unsigned short* __restrict__ p2h,
    const unsigned short* __restrict__ Bfrag, const float* __restrict__ conv_b,
    float* __restrict__ H)
{
    __shared__ unsigned short embS[SLOTS * ESTR];   // [slot][e] bf16
    __shared__ int xS[LSEQ], p1S[LSEQ], p2S[LSEQ];
    const int n = blockIdx.x, tid = threadIdx.x;
    const int lane = tid & 63;
    const int wave = __builtin_amdgcn_readfirstlane(tid >> 6);
    const int nt0  = wave * 4;
    const int m    = lane & 15;
    const int quad = lane >> 4;

    // ---- this wave's B fragments -> registers (96 VGPRs), issued first
    short8 Bw[4][KSTEPS];
    #pragma unroll
    for (int t = 0; t < 4; ++t)
        #pragma unroll
        for (int ks = 0; ks < KSTEPS; ++ks)
            Bw[t][ks] = *(const short8*)(Bfrag + ((size_t)((nt0 + t) * KSTEPS + ks) * 64 + lane) * 8);

    // ---- stage index rows + zero pad rows (only cols 0..63 are ever read)
    if (tid < LSEQ) {
        xS[tid]  = X [n * LSEQ + tid];
        p1S[tid] = P1[n * LSEQ + tid];
    } else {
        int t = tid - LSEQ;
        p2S[t] = P2[n * LSEQ + t];
        if (t < 64) {
            int r = (t & 32) ? (SLOTS - 1) : 0;
            *(unsigned*)(embS + r * ESTR + (t & 31) * 2) = 0u;
        }
    }
    __syncthreads();

    // ---- pair-gather into LDS: token l, pair pr (2 bf16 = 4 B)
    #pragma unroll
    for (int it = 0; it < (LSEQ * 32) / 256; ++it) {
        int i = tid + it * 256;
        int l = i >> 5, pr = i & 31;
        unsigned val;
        if (TBL) {
            if (pr < 25)       val = *(const unsigned*)(wembh + (size_t)xS[l] * VEC + pr * 2);
            else if (pr < 28)  val = *(const unsigned*)(p1h + p1S[l] * 6 + (pr - 25) * 2);
            else if (pr < 31)  val = *(const unsigned*)(p2h + p2S[l] * 6 + (pr - 28) * 2);
            else               val = 0u;
        } else {
            float a = 0.f, b = 0.f;
            if (pr < 25) {
                float2 f = *(const float2*)(wemb + (size_t)xS[l] * VEC + pr * 2);
                a = f.x; b = f.y;
            } else if (pr < 28) {
                int j0 = (pr - 25) * 2;
                a = p1emb[p1S[l] * POS + j0];
                b = (j0 + 1 < POS) ? p1emb[p1S[l] * POS + j0 + 1] : 0.f;
            } else if (pr < 31) {
                int j0 = (pr - 28) * 2;
                a = p2emb[p2S[l] * POS + j0];
                b = (j0 + 1 < POS) ? p2emb[p2S[l] * POS + j0 + 1] : 0.f;
            }
            union { unsigned short s[2]; unsigned u; } o;
            o.s[0] = f2bf(a); o.s[1] = f2bf(b);
            val = o.u;
        }
        *(unsigned*)(embS + (l + 1) * ESTR + pr * 2) = val;
    }
    __syncthreads();

    // ---- main loop: 8 M-tiles of 16 output positions; 6 ds_read : 24 MFMA per mt
    float maxv[4][4];
    #pragma unroll
    for (int t = 0; t < 4; ++t)
        #pragma unroll
        for (int r = 0; r < 4; ++r) maxv[t][r] = -1e30f;

    for (int mt = 0; mt < 8; ++mt) {
        short8 A[KSTEPS];
        #pragma unroll
        for (int ks = 0; ks < KSTEPS; ++ks) {
            int tap = ks >> 1;
            int col = (ks & 1) * 32 + quad * 8;
            int row = mt * 16 + m + tap;            // slot (l+tap), +1 shift folded in
            A[ks] = *(const short8*)(embS + row * ESTR + col);
        }
        f32x4 acc[4];
        #pragma unroll
        for (int t = 0; t < 4; ++t) acc[t] = (f32x4){0.f, 0.f, 0.f, 0.f};
        #pragma unroll
        for (int ks = 0; ks < KSTEPS; ++ks)
            #pragma unroll
            for (int t = 0; t < 4; ++t)
                acc[t] = __builtin_amdgcn_mfma_f32_16x16x32_bf16(A[ks], Bw[t][ks], acc[t], 0, 0, 0);
        #pragma unroll
        for (int t = 0; t < 4; ++t)
            #pragma unroll
            for (int r = 0; r < 4; ++r)
                maxv[t][r] = fmaxf(maxv[t][r], acc[t][r]);
    }

    // ---- reduce rows (4 regs, then quads via xor 16/32) -> bias + relu -> H
    #pragma unroll
    for (int t = 0; t < 4; ++t) {
        float v = fmaxf(fmaxf(maxv[t][0], maxv[t][1]), fmaxf(maxv[t][2], maxv[t][3]));
        v = fmaxf(v, __shfl_xor(v, 16));
        v = fmaxf(v, __shfl_xor(v, 32));
        int c = (nt0 + t) * 16 + lane;
        if (lane < 16 && c < HIDD)
            H[(size_t)n * HSTR + c] = fmaxf(v + conv_b[c], 0.f);
    }
}

// ---- Kernel 3: wave-per-bag softmax attention + fused 4-bag classifier ----
// block = 4 waves = 4 bags; grid = 125. Channels distributed: lane c owns
// c, c+64, c+128, c+192. Single barrier (classifier LDS bounce).
__global__ __launch_bounds__(256) void attn(
    const float* __restrict__ H, const float* __restrict__ rel_w, const float* __restrict__ rel_b,
    const int* __restrict__ relation, const int* __restrict__ scope,
    float* __restrict__ out)
{
    __shared__ float repS[4][HSTR];
    const int tid = threadIdx.x, lane = tid & 63, wave = tid >> 6;
    const int b = blockIdx.x * 4 + wave;
    const int start = scope[2 * b];
    int ns = scope[2 * b + 1] - start;
    if (ns > 8) ns = 8;
    const int rel = relation[b];

    float q[4], h[8][4];
    #pragma unroll
    for (int k = 0; k < 4; ++k) {
        int c = lane + 64 * k;
        q[k] = (c < HIDD) ? rel_w[rel * HIDD + c] : 0.f;
    }
    #pragma unroll
    for (int s = 0; s < 8; ++s)
        #pragma unroll
        for (int k = 0; k < 4; ++k) {
            int c = lane + 64 * k;
            h[s][k] = (s < ns && c < HIDD) ? H[(size_t)(start + s) * HSTR + c] : 0.f;
        }

    float logit[8];
    #pragma unroll
    for (int s = 0; s < 8; ++s) {
        float t = q[0] * h[s][0] + q[1] * h[s][1] + q[2] * h[s][2] + q[3] * h[s][3];
        #pragma unroll
        for (int off = 32; off > 0; off >>= 1) t += __shfl_xor(t, off);
        logit[s] = t;   // all lanes hold it
    }

    float mx = -1e30f;
    for (int s = 0; s < ns; ++s) mx = fmaxf(mx, logit[s]);
    float a[8], den = 0.f;
    #pragma unroll
    for (int s = 0; s < 8; ++s) { a[s] = (s < ns) ? expf(logit[s] - mx) : 0.f; den += a[s]; }
    float inv = 1.f / den;

    #pragma unroll
    for (int k = 0; k < 4; ++k) {
        float r = 0.f;
        #pragma unroll
        for (int s = 0; s < 8; ++s) r += a[s] * h[s][k];
        int c = lane + 64 * k;
        if (c < HSTR) repS[wave][c] = r * inv;   // cols 230/231 get 0 (h was 0)
    }
    __syncthreads();

    // classifier: group g (25 of 32) x 8 lanes; one rel_w read feeds all 4 bags
    int g = tid >> 3, l8 = tid & 7;
    if (g < NREL) {
        float p0 = 0.f, p1 = 0.f, p2 = 0.f, p3 = 0.f;
        for (int c = l8; c < HIDD; c += 8) {
            float wv = rel_w[g * HIDD + c];
            p0 += repS[0][c] * wv;
            p1 += repS[1][c] * wv;
            p2 += repS[2][c] * wv;
            p3 += repS[3][c] * wv;
        }
        #pragma unroll
        for (int off = 4; off > 0; off >>= 1) {
            p0 += __shfl_xor(p0, off);
            p1 += __shfl_xor(p1, off);
            p2 += __shfl_xor(p2, off);
            p3 += __shfl_xor(p3, off);
        }
        if (l8 == 0) {
            int b0 = blockIdx.x * 4;
            float rb = rel_b[g];
            out[(b0 + 0) * NREL + g] = p0 + rb;
            out[(b0 + 1) * NREL + g] = p1 + rb;
            out[(b0 + 2) * NREL + g] = p2 + rb;
            out[(b0 + 3) * NREL + g] = p3 + rb;
        }
    }
}

extern "C" void kernel_launch(void* const* d_in, const int* in_sizes, int n_in,
                              void* d_out, int out_size, void* d_ws, size_t ws_size,
                              hipStream_t stream) {
    const int*   X        = (const int*)d_in[0];
    const int*   P1       = (const int*)d_in[1];
    const int*   P2       = (const int*)d_in[2];
    const int*   scope    = (const int*)d_in[5];
    const int*   relation = (const int*)d_in[6];
    const float* wemb     = (const float*)d_in[7];
    const float* p1emb    = (const float*)d_in[8];
    const float* p2emb    = (const float*)d_in[9];
    const float* conv_w   = (const float*)d_in[10];
    const float* conv_b   = (const float*)d_in[11];
    const float* rel_w    = (const float*)d_in[12];
    const float* rel_b    = (const float*)d_in[13];

    // workspace layout
    char* ws = (char*)d_ws;
    float* H = (float*)ws;                                   // 4000*232*4   = 3,712,000
    size_t off = (size_t)NSENT * HSTR * 4;
    unsigned short* Bfrag = (unsigned short*)(ws + off);     // 16*6*64*8*2  =    98,304
    off += (size_t)NTILEP * KSTEPS * 64 * 8 * 2;
    unsigned short* wembh = (unsigned short*)(ws + off);     // 50002*50*2   = 5,000,200
    off += (size_t)50002 * VEC * 2;
    unsigned short* p1h = (unsigned short*)(ws + off);       // 201*6*2
    off += 201 * 6 * 2;
    unsigned short* p2h = (unsigned short*)(ws + off);
    off += 201 * 6 * 2;
    const bool use_tbl = (ws_size >= off);

    if (use_tbl) {
        hipLaunchKernelGGL(prep, dim3(WBLK + PBLK + TBLK), dim3(256), 0, stream,
                           wemb, p1emb, p2emb, conv_w, wembh, p1h, p2h, Bfrag, 0);
        hipLaunchKernelGGL((encoder<true>), dim3(NSENT), dim3(256), 0, stream,
                           X, P1, P2, wemb, p1emb, p2emb, wembh, p1h, p2h, Bfrag, conv_b, H);
    } else {
        hipLaunchKernelGGL(prep, dim3(TBLK), dim3(256), 0, stream,
                           wemb, p1emb, p2emb, conv_w, wembh, p1h, p2h, Bfrag, WBLK + PBLK);
        hipLaunchKernelGGL((encoder<false>), dim3(NSENT), dim3(256), 0, stream,
                           X, P1, P2, wemb, p1emb, p2emb, wembh, p1h, p2h, Bfrag, conv_b, H);
    }
    hipLaunchKernelGGL(attn, dim3(NBAG / 4), dim3(256), 0, stream,
                       H, rel_w, rel_b, relation, scope, (float*)d_out);
}

// Round 6
// 217.519 us; speedup vs baseline: 1.0617x; 1.0617x over previous
//
#include <hip/hip_runtime.h>

#define NSENT 4000
#define LSEQ  128
#define VEC   50
#define POS   5
#define EMBD  60      // VEC + 2*POS
#define HIDD  230
#define HSTR  232     // padded channel stride for H
#define NBAG  500
#define NREL  25
#define NTILEP 16     // padded N-tile count (15 real, tile 15 = zeros)
#define KSTEPS 6      // K = 192 (3 taps * 64 e-slots), 6 MFMA K-steps of 32
#define ESTR  72      // LDS row stride in bf16 shorts (144 B, 16B-aligned rows; 2-way=free)
#define SLOTS 130     // l+1 shift; rows 0/129 are SAME-pad zeros
#define WROW  52      // wembh padded row (104 B -> every row 8B-aligned)

// e-slot mapping (A and B MUST agree):
//   e 0..49  = wemb dims 0..49      (e50,51 = 0, wembh pad cols)
//   e 52..55 = p1 dims 0..3         (8B slot)
//   e 56..59 = p2 dims 0..3         (8B slot)
//   e 60     = p1 dim 4, e61 = 0    (4B tail from p1h[4..5])
//   e 62     = p2 dim 4, e63 = 0    (4B tail from p2h[4..5])
typedef __attribute__((ext_vector_type(8))) short short8;   // 8 bf16 = 4 VGPRs
typedef __attribute__((ext_vector_type(4))) float f32x4;

__device__ __forceinline__ unsigned short f2bf(float f) {
    union { float f; unsigned u; } v; v.f = f;
    unsigned u = v.u + 0x7FFF + ((v.u >> 16) & 1);   // RNE
    return (unsigned short)(u >> 16);
}

// ---- fused prep: [0,WBLK) wordtab | [WBLK,WBLK+PBLK) postab | rest transpose_w ----
#define WDWORDS (50002 * 26)     // wembh as dword pairs, 26 per row
#define WBLK    5079             // ceil(WDWORDS/256)
#define PBLK    13               // ceil(2*201*8/256)
#define TBLK    192              // NTILEP*KSTEPS*64*8/256
__global__ __launch_bounds__(256) void prep(const float* __restrict__ wemb,
                                            const float* __restrict__ p1emb,
                                            const float* __restrict__ p2emb,
                                            const float* __restrict__ conv_w,
                                            unsigned short* __restrict__ wembh,
                                            unsigned short* __restrict__ p1h,
                                            unsigned short* __restrict__ p2h,
                                            unsigned short* __restrict__ Bfrag,
                                            int base) {
    int blk = blockIdx.x + base;
    if (blk < WBLK) {
        int idx = blk * 256 + threadIdx.x;
        if (idx < WDWORDS) {
            int row = idx / 26, c2 = idx - row * 26;
            int c0 = c2 * 2;
            union { unsigned short s[2]; unsigned u; } o;
            if (c0 < VEC) {           // c0, c0+1 both < 50 (c0 even, <50 => c0+1 <= 49)
                float2 f = *(const float2*)(wemb + (size_t)row * VEC + c0);
                o.s[0] = f2bf(f.x); o.s[1] = f2bf(f.y);
            } else { o.u = 0u; }      // pad cols 50,51
            *(unsigned*)(wembh + (size_t)row * WROW + c0) = o.u;
        }
    } else if (blk < WBLK + PBLK) {
        int idx = (blk - WBLK) * 256 + threadIdx.x;
        if (idx < 2 * 201 * 8) {
            int t = idx >= 201 * 8;
            int rem = idx - t * 201 * 8;
            int row = rem >> 3, col = rem & 7;
            const float* src = t ? p2emb : p1emb;
            unsigned short* dst = t ? p2h : p1h;
            dst[rem] = (col < POS) ? f2bf(src[row * POS + col]) : 0;
        }
    } else {
        int idx = (blk - WBLK - PBLK) * 256 + threadIdx.x;
        // B layout for mfma_f32_16x16x32_bf16: B[n = lane&15][k = (lane>>4)*8 + j]
        int j    = idx & 7;
        int lane = (idx >> 3) & 63;
        int t    = idx >> 9;
        int ks   = t % KSTEPS;
        int nt   = t / KSTEPS;
        int c    = nt * 16 + (lane & 15);
        int klin = ks * 32 + (lane >> 4) * 8 + j;
        int tap  = klin >> 6;
        int e    = klin & 63;
        float v  = 0.f;
        if (c < HIDD) {
            int eidx = -1;
            if (e < 50)                 eidx = e;            // wemb
            else if (e >= 52 && e < 56) eidx = 50 + (e - 52); // p1[0..3]
            else if (e >= 56 && e < 60) eidx = 55 + (e - 56); // p2[0..3]
            else if (e == 60)           eidx = 54;            // p1[4]
            else if (e == 62)           eidx = 59;            // p2[4]
            if (eidx >= 0) v = conv_w[(c * EMBD + eidx) * 3 + tap];
        }
        Bfrag[idx] = f2bf(v);
    }
}

// ---- Kernel 2: gather + conv1d(k=3,SAME) via bf16 MFMA + maxpool + bias + relu ----
// one block = 256 thr = 4 waves per sentence; wave w owns N-tiles {4w..4w+3}.
// __launch_bounds__(256,2): VGPR cap 256 so B (96 VGPRs) stays resident —
// R5 regression root cause was the default heuristic capping at 120.
// A-frag A[m=lane&15][k=quad*8+j] from LDS; C tile col=lane&15, row=quad*4+reg
template <bool TBL>
__global__ __launch_bounds__(256, 2) void encoder(
    const int*   __restrict__ X,  const int* __restrict__ P1, const int* __restrict__ P2,
    const float* __restrict__ wemb, const float* __restrict__ p1emb, const float* __restrict__ p2emb,
    const unsigned short* __restrict__ wembh, const unsigned short* __restrict__ p1h,
    const unsigned short* __restrict__ p2h,
    const unsigned short* __restrict__ Bfrag, const float* __restrict__ conv_b,
    float* __restrict__ H)
{
    __shared__ unsigned short embS[SLOTS * ESTR];   // [slot][e] bf16
    __shared__ int xS[LSEQ], p1S[LSEQ], p2S[LSEQ];
    const int n = blockIdx.x, tid = threadIdx.x;
    const int lane = tid & 63;
    const int wave = __builtin_amdgcn_readfirstlane(tid >> 6);
    const int nt0  = wave * 4;
    const int m    = lane & 15;
    const int quad = lane >> 4;

    // ---- this wave's B fragments -> registers (96 VGPRs), issued first
    short8 Bw[4][KSTEPS];
    #pragma unroll
    for (int t = 0; t < 4; ++t)
        #pragma unroll
        for (int ks = 0; ks < KSTEPS; ++ks)
            Bw[t][ks] = *(const short8*)(Bfrag + ((size_t)((nt0 + t) * KSTEPS + ks) * 64 + lane) * 8);

    // ---- stage index rows + zero pad rows (slots 0, 129: all 64 e-slots)
    if (tid < LSEQ) {
        xS[tid]  = X [n * LSEQ + tid];
        p1S[tid] = P1[n * LSEQ + tid];
    } else {
        int t = tid - LSEQ;
        p2S[t] = P2[n * LSEQ + t];
        if (t < 64) {
            int r = (t & 32) ? (SLOTS - 1) : 0;
            *(unsigned*)(embS + r * ESTR + (t & 31) * 2) = 0u;
        }
    }
    __syncthreads();

    // ---- gather into LDS: 16 lanes per token, 8B single-table segments
    #pragma unroll
    for (int it = 0; it < (LSEQ * 16) / 256; ++it) {
        int i = tid + it * 256;
        int l = i >> 4, pr2 = i & 15;
        unsigned short* dst = embS + (l + 1) * ESTR;
        if (TBL) {
            if (pr2 <= 12) {            // wemb shorts 4*pr2 .. +3 -> e 0..51
                uint2 v = *(const uint2*)(wembh + (size_t)xS[l] * WROW + pr2 * 4);
                *(uint2*)(dst + pr2 * 4) = v;
            } else if (pr2 == 13) {     // p1[0..3] -> e52..55
                uint2 v = *(const uint2*)(p1h + p1S[l] * 8);
                *(uint2*)(dst + 52) = v;
            } else if (pr2 == 14) {     // p2[0..3] -> e56..59
                uint2 v = *(const uint2*)(p2h + p2S[l] * 8);
                *(uint2*)(dst + 56) = v;
            } else {                    // tails: p1[4],0 -> e60,61 ; p2[4],0 -> e62,63
                unsigned a = *(const unsigned*)(p1h + p1S[l] * 8 + 4);
                unsigned b = *(const unsigned*)(p2h + p2S[l] * 8 + 4);
                *(unsigned*)(dst + 60) = a;
                *(unsigned*)(dst + 62) = b;
            }
        } else {
            // slow fallback: 2 shorts per lane via f32 tables, two sub-iterations
            #pragma unroll
            for (int h2 = 0; h2 < 2; ++h2) {
                int pr = pr2 * 2 + h2;          // 0..31 pair index, e = 2*pr
                float a = 0.f, bb = 0.f;
                if (pr < 25) {
                    float2 f = *(const float2*)(wemb + (size_t)xS[l] * VEC + pr * 2);
                    a = f.x; bb = f.y;
                } else if (pr == 26) { a = p1emb[p1S[l] * POS + 0]; bb = p1emb[p1S[l] * POS + 1]; }
                else if (pr == 27)   { a = p1emb[p1S[l] * POS + 2]; bb = p1emb[p1S[l] * POS + 3]; }
                else if (pr == 28)   { a = p2emb[p2S[l] * POS + 0]; bb = p2emb[p2S[l] * POS + 1]; }
                else if (pr == 29)   { a = p2emb[p2S[l] * POS + 2]; bb = p2emb[p2S[l] * POS + 3]; }
                else if (pr == 30)   { a = p1emb[p1S[l] * POS + 4]; }
                else if (pr == 31)   { a = p2emb[p2S[l] * POS + 4]; }
                union { unsigned short s[2]; unsigned u; } o;
                o.s[0] = f2bf(a); o.s[1] = f2bf(bb);
                *(unsigned*)(dst + pr * 2) = o.u;
            }
        }
    }
    __syncthreads();

    // ---- main loop: 8 M-tiles; per mt: 6 ds_read_b128 : 24 MFMA
    float maxv[4][4];
    #pragma unroll
    for (int t = 0; t < 4; ++t)
        #pragma unroll
        for (int r = 0; r < 4; ++r) maxv[t][r] = -1e30f;

    for (int mt = 0; mt < 8; ++mt) {
        short8 A[KSTEPS];
        #pragma unroll
        for (int ks = 0; ks < KSTEPS; ++ks) {
            int tap = ks >> 1;
            int col = (ks & 1) * 32 + quad * 8;
            int row = mt * 16 + m + tap;            // slot (l+tap), +1 shift folded in
            A[ks] = *(const short8*)(embS + row * ESTR + col);
        }
        f32x4 acc[4];
        #pragma unroll
        for (int t = 0; t < 4; ++t) acc[t] = (f32x4){0.f, 0.f, 0.f, 0.f};
        #pragma unroll
        for (int ks = 0; ks < KSTEPS; ++ks)
            #pragma unroll
            for (int t = 0; t < 4; ++t)
                acc[t] = __builtin_amdgcn_mfma_f32_16x16x32_bf16(A[ks], Bw[t][ks], acc[t], 0, 0, 0);
        #pragma unroll
        for (int t = 0; t < 4; ++t)
            #pragma unroll
            for (int r = 0; r < 4; ++r)
                maxv[t][r] = fmaxf(maxv[t][r], acc[t][r]);
    }

    // ---- reduce rows (4 regs, then quads via xor 16/32) -> bias + relu -> H
    #pragma unroll
    for (int t = 0; t < 4; ++t) {
        float v = fmaxf(fmaxf(maxv[t][0], maxv[t][1]), fmaxf(maxv[t][2], maxv[t][3]));
        v = fmaxf(v, __shfl_xor(v, 16));
        v = fmaxf(v, __shfl_xor(v, 32));
        int c = (nt0 + t) * 16 + lane;
        if (lane < 16 && c < HIDD)
            H[(size_t)n * HSTR + c] = fmaxf(v + conv_b[c], 0.f);
    }
}

// ---- Kernel 3: one wave per bag, zero barriers, all state in registers ----
__global__ __launch_bounds__(64) void attn(
    const float* __restrict__ H, const float* __restrict__ rel_w, const float* __restrict__ rel_b,
    const int* __restrict__ relation, const int* __restrict__ scope,
    float* __restrict__ out)
{
    const int b = blockIdx.x, lane = threadIdx.x;
    const int start = scope[2 * b];
    int ns = scope[2 * b + 1] - start;
    if (ns > 8) ns = 8;
    const int rel = relation[b];

    float q[4], h[8][4];
    #pragma unroll
    for (int k = 0; k < 4; ++k) {
        int c = lane + 64 * k;
        q[k] = (c < HIDD) ? rel_w[rel * HIDD + c] : 0.f;
    }
    #pragma unroll
    for (int s = 0; s < 8; ++s)
        #pragma unroll
        for (int k = 0; k < 4; ++k) {
            int c = lane + 64 * k;
            h[s][k] = (s < ns && c < HIDD) ? H[(size_t)(start + s) * HSTR + c] : 0.f;
        }

    float logit[8];
    #pragma unroll
    for (int s = 0; s < 8; ++s) {
        float t = q[0] * h[s][0] + q[1] * h[s][1] + q[2] * h[s][2] + q[3] * h[s][3];
        #pragma unroll
        for (int off = 32; off > 0; off >>= 1) t += __shfl_xor(t, off);
        logit[s] = t;   // all lanes hold it
    }

    float mx = -1e30f;
    for (int s = 0; s < ns; ++s) mx = fmaxf(mx, logit[s]);
    float a[8], den = 0.f;
    #pragma unroll
    for (int s = 0; s < 8; ++s) { a[s] = (s < ns) ? expf(logit[s] - mx) : 0.f; den += a[s]; }
    float inv = 1.f / den;

    float rep[4];
    #pragma unroll
    for (int k = 0; k < 4; ++k) {
        float r = 0.f;
        #pragma unroll
        for (int s = 0; s < 8; ++s) r += a[s] * h[s][k];
        rep[k] = r * inv;
    }

    // classifier: 25 rows of rel_w, coalesced wave reads (L2-broadcast)
    #pragma unroll 5
    for (int g = 0; g < NREL; ++g) {
        float t = 0.f;
        #pragma unroll
        for (int k = 0; k < 4; ++k) {
            int c = lane + 64 * k;
            t += (c < HIDD) ? rel_w[g * HIDD + c] * rep[k] : 0.f;
        }
        #pragma unroll
        for (int off = 32; off > 0; off >>= 1) t += __shfl_xor(t, off);
        if (lane == 0) out[b * NREL + g] = t + rel_b[g];
    }
}

extern "C" void kernel_launch(void* const* d_in, const int* in_sizes, int n_in,
                              void* d_out, int out_size, void* d_ws, size_t ws_size,
                              hipStream_t stream) {
    const int*   X        = (const int*)d_in[0];
    const int*   P1       = (const int*)d_in[1];
    const int*   P2       = (const int*)d_in[2];
    const int*   scope    = (const int*)d_in[5];
    const int*   relation = (const int*)d_in[6];
    const float* wemb     = (const float*)d_in[7];
    const float* p1emb    = (const float*)d_in[8];
    const float* p2emb    = (const float*)d_in[9];
    const float* conv_w   = (const float*)d_in[10];
    const float* conv_b   = (const float*)d_in[11];
    const float* rel_w    = (const float*)d_in[12];
    const float* rel_b    = (const float*)d_in[13];

    // workspace layout (all 8B-aligned)
    char* ws = (char*)d_ws;
    float* H = (float*)ws;                                   // 4000*232*4    = 3,712,000
    size_t off = (size_t)NSENT * HSTR * 4;
    unsigned short* Bfrag = (unsigned short*)(ws + off);     // 16*6*64*8*2   =    98,304
    off += (size_t)NTILEP * KSTEPS * 64 * 8 * 2;
    unsigned short* wembh = (unsigned short*)(ws + off);     // 50002*52*2    = 5,200,208
    off += (size_t)50002 * WROW * 2;
    unsigned short* p1h = (unsigned short*)(ws + off);       // 201*8*2       =     3,216
    off += 201 * 8 * 2;
    unsigned short* p2h = (unsigned short*)(ws + off);
    off += 201 * 8 * 2;
    const bool use_tbl = (ws_size >= off);

    if (use_tbl) {
        hipLaunchKernelGGL(prep, dim3(WBLK + PBLK + TBLK), dim3(256), 0, stream,
                           wemb, p1emb, p2emb, conv_w, wembh, p1h, p2h, Bfrag, 0);
        hipLaunchKernelGGL((encoder<true>), dim3(NSENT), dim3(256), 0, stream,
                           X, P1, P2, wemb, p1emb, p2emb, wembh, p1h, p2h, Bfrag, conv_b, H);
    } else {
        hipLaunchKernelGGL(prep, dim3(TBLK), dim3(256), 0, stream,
                           wemb, p1emb, p2emb, conv_w, wembh, p1h, p2h, Bfrag, WBLK + PBLK);
        hipLaunchKernelGGL((encoder<false>), dim3(NSENT), dim3(256), 0, stream,
                           X, P1, P2, wemb, p1emb, p2emb, wembh, p1h, p2h, Bfrag, conv_b, H);
    }
    hipLaunchKernelGGL(attn, dim3(NBAG), dim3(64), 0, stream,
                       H, rel_w, rel_b, relation, scope, (float*)d_out);
}

// Round 7
// 187.682 us; speedup vs baseline: 1.2305x; 1.1590x over previous
//
#include <hip/hip_runtime.h>
#include <hip/hip_bf16.h>

#define NSENT 4000
#define LSEQ  128
#define VEC   50
#define POS   5
#define EMBD  60      // VEC + 2*POS
#define HIDD  230
#define HSTR  232     // padded channel stride for H
#define NBAG  500
#define NREL  25
#define NTILEP 16     // padded N-tile count (15 real, tile 15 = zeros)
#define KSTEPS 6      // K = 192 (3 taps * 64 e-slots), 6 MFMA K-steps of 32
#define ESTR  72      // LDS row stride in bf16 shorts (144 B; 2-way bank alias = free)
#define SLOTS 130     // l+1 shift; rows 0/129 are SAME-pad zeros

// e-slot mapping (A and B MUST agree):
//   e 0..49  = wemb dims 0..49      (e50,51 = 0)
//   e 52..55 = p1 dims 0..3
//   e 56..59 = p2 dims 0..3
//   e 60     = p1 dim 4, e61 = 0
//   e 62     = p2 dim 4, e63 = 0
typedef __attribute__((ext_vector_type(8))) short short8;   // 8 bf16 = 4 VGPRs
typedef __attribute__((ext_vector_type(4))) float f32x4;

__device__ __forceinline__ unsigned short f2bf(float f) {
    union { float f; unsigned u; } v; v.f = f;
    unsigned u = v.u + 0x7FFF + ((v.u >> 16) & 1);   // RNE
    return (unsigned short)(u >> 16);
}

// packed f32x2 -> bf16x2 (v_cvt_pk_bf16_f32 on gfx950), low short = first arg
__device__ __forceinline__ unsigned pk(float a, float b) {
    __hip_bfloat162 h = __float22bfloat162_rn(float2{a, b});
    union { __hip_bfloat162 h; unsigned u; } c; c.h = h;
    return c.u;
}

// ---- prep: conv_w [HID][EMB][3] -> Bfrag[ntile][kstep][lane][8] (bf16) ----
// B layout for mfma_f32_16x16x32_bf16: B[n = lane&15][k = (lane>>4)*8 + j]
__global__ __launch_bounds__(256) void prep_b(const float* __restrict__ conv_w,
                                              unsigned short* __restrict__ Bfrag) {
    int idx = blockIdx.x * 256 + threadIdx.x;
    if (idx >= NTILEP * KSTEPS * 64 * 8) return;
    int j    = idx & 7;
    int lane = (idx >> 3) & 63;
    int t    = idx >> 9;
    int ks   = t % KSTEPS;
    int nt   = t / KSTEPS;
    int c    = nt * 16 + (lane & 15);
    int klin = ks * 32 + (lane >> 4) * 8 + j;
    int tap  = klin >> 6;
    int e    = klin & 63;
    float v  = 0.f;
    if (c < HIDD) {
        int eidx = -1;
        if (e < 50)                 eidx = e;             // wemb dims
        else if (e >= 52 && e < 56) eidx = 50 + (e - 52); // p1[0..3]
        else if (e >= 56 && e < 60) eidx = 55 + (e - 56); // p2[0..3]
        else if (e == 60)           eidx = 54;            // p1[4]
        else if (e == 62)           eidx = 59;            // p2[4]
        if (eidx >= 0) v = conv_w[(c * EMBD + eidx) * 3 + tap];
    }
    Bfrag[idx] = f2bf(v);
}

// ---- Kernel 2: gather(+cvt) + conv1d(k=3,SAME) via bf16 MFMA + maxpool + relu ----
// one block = 512 thr = 8 waves per sentence; wave w owns N-tiles {2w, 2w+1}
// (R4-proven structure: B = 48 VGPRs/wave stays resident, VGPR_Count ~64).
// Gather converts f32 tables in-kernel via packed cvt — no bf16 table prep.
// A-frag A[m=lane&15][k=quad*8+j] from LDS; C tile col=lane&15, row=quad*4+reg
__global__ __launch_bounds__(512, 4) void encoder(
    const int*   __restrict__ X,  const int* __restrict__ P1, const int* __restrict__ P2,
    const float* __restrict__ wemb, const float* __restrict__ p1emb, const float* __restrict__ p2emb,
    const unsigned short* __restrict__ Bfrag, const float* __restrict__ conv_b,
    float* __restrict__ H)
{
    __shared__ unsigned short embS[SLOTS * ESTR];   // [slot][e] bf16
    __shared__ int xS[LSEQ], p1S[LSEQ], p2S[LSEQ];
    const int n = blockIdx.x, tid = threadIdx.x;
    const int lane = tid & 63;
    const int wave = __builtin_amdgcn_readfirstlane(tid >> 6);
    const int nt0  = wave * 2;
    const int m    = lane & 15;
    const int quad = lane >> 4;

    // ---- this wave's B fragments -> registers (48 VGPRs), issued first
    short8 Bw[2][KSTEPS];
    #pragma unroll
    for (int t = 0; t < 2; ++t)
        #pragma unroll
        for (int ks = 0; ks < KSTEPS; ++ks)
            Bw[t][ks] = *(const short8*)(Bfrag + ((size_t)((nt0 + t) * KSTEPS + ks) * 64 + lane) * 8);

    // ---- stage index rows + zero pad rows (slots 0, 129)
    if (tid < LSEQ)                  xS[tid]        = X [n * LSEQ + tid];
    else if (tid < 2 * LSEQ)         p1S[tid - 128] = P1[n * LSEQ + tid - 128];
    else if (tid < 3 * LSEQ)         p2S[tid - 256] = P2[n * LSEQ + tid - 256];
    else if (tid < 3 * LSEQ + 64) {
        int t = tid - 3 * LSEQ;
        int r = (t & 32) ? (SLOTS - 1) : 0;
        *(unsigned*)(embS + r * ESTR + (t & 31) * 2) = 0u;
    }
    __syncthreads();

    // ---- gather: 16 lanes per token, f32 loads + packed cvt, 8B LDS writes
    #pragma unroll
    for (int it = 0; it < (LSEQ * 16) / 512; ++it) {
        int i = tid + it * 512;
        int l = i >> 4, j = i & 15;
        unsigned short* dst = embS + (l + 1) * ESTR;
        uint2 v;
        if (j < 13) {                 // e 4j..4j+3 from wemb (rows are 8B-aligned: 200 B)
            const float* src = wemb + (size_t)xS[l] * VEC + j * 4;
            float2 fa = *(const float2*)(src);
            float a2 = 0.f, a3 = 0.f;
            if (j < 12) { float2 fb = *(const float2*)(src + 2); a2 = fb.x; a3 = fb.y; }
            v.x = pk(fa.x, fa.y); v.y = pk(a2, a3);
        } else if (j == 13) {         // p1[0..3] -> e52..55 (4B-aligned rows: scalar)
            const float* p = p1emb + p1S[l] * POS;
            v.x = pk(p[0], p[1]); v.y = pk(p[2], p[3]);
        } else if (j == 14) {         // p2[0..3] -> e56..59
            const float* p = p2emb + p2S[l] * POS;
            v.x = pk(p[0], p[1]); v.y = pk(p[2], p[3]);
        } else {                      // tails -> e60..63
            float a = p1emb[p1S[l] * POS + 4];
            float b = p2emb[p2S[l] * POS + 4];
            v.x = pk(a, 0.f); v.y = pk(b, 0.f);
        }
        *(uint2*)(dst + (j < 13 ? j * 4 : 52 + (j - 13) * 4)) = v;
    }
    __syncthreads();

    // ---- main loop: 8 M-tiles of 16 positions; per mt: 6 ds_read_b128 : 12 MFMA
    float maxv[2][4];
    #pragma unroll
    for (int t = 0; t < 2; ++t)
        #pragma unroll
        for (int r = 0; r < 4; ++r) maxv[t][r] = -1e30f;

    for (int mt = 0; mt < 8; ++mt) {
        short8 A[KSTEPS];
        #pragma unroll
        for (int ks = 0; ks < KSTEPS; ++ks) {
            int tap = ks >> 1;
            int col = (ks & 1) * 32 + quad * 8;
            int row = mt * 16 + m + tap;            // slot (l+tap), +1 shift folded in
            A[ks] = *(const short8*)(embS + row * ESTR + col);
        }
        f32x4 acc[2];
        #pragma unroll
        for (int t = 0; t < 2; ++t) acc[t] = (f32x4){0.f, 0.f, 0.f, 0.f};
        #pragma unroll
        for (int ks = 0; ks < KSTEPS; ++ks)
            #pragma unroll
            for (int t = 0; t < 2; ++t)
                acc[t] = __builtin_amdgcn_mfma_f32_16x16x32_bf16(A[ks], Bw[t][ks], acc[t], 0, 0, 0);
        #pragma unroll
        for (int t = 0; t < 2; ++t)
            #pragma unroll
            for (int r = 0; r < 4; ++r)
                maxv[t][r] = fmaxf(maxv[t][r], acc[t][r]);
    }

    // ---- reduce rows (4 regs, then quads via xor 16/32) -> bias + relu -> H
    #pragma unroll
    for (int t = 0; t < 2; ++t) {
        float v = fmaxf(fmaxf(maxv[t][0], maxv[t][1]), fmaxf(maxv[t][2], maxv[t][3]));
        v = fmaxf(v, __shfl_xor(v, 16));
        v = fmaxf(v, __shfl_xor(v, 32));
        int c = (nt0 + t) * 16 + lane;
        if (lane < 16 && c < HIDD)
            H[(size_t)n * HSTR + c] = fmaxf(v + conv_b[c], 0.f);
    }
}

// ---- Kernel 3: one wave per bag, zero barriers, all state in registers ----
__global__ __launch_bounds__(64) void attn(
    const float* __restrict__ H, const float* __restrict__ rel_w, const float* __restrict__ rel_b,
    const int* __restrict__ relation, const int* __restrict__ scope,
    float* __restrict__ out)
{
    const int b = blockIdx.x, lane = threadIdx.x;
    const int start = scope[2 * b];
    int ns = scope[2 * b + 1] - start;
    if (ns > 8) ns = 8;
    const int rel = relation[b];

    float q[4], h[8][4];
    #pragma unroll
    for (int k = 0; k < 4; ++k) {
        int c = lane + 64 * k;
        q[k] = (c < HIDD) ? rel_w[rel * HIDD + c] : 0.f;
    }
    #pragma unroll
    for (int s = 0; s < 8; ++s)
        #pragma unroll
        for (int k = 0; k < 4; ++k) {
            int c = lane + 64 * k;
            h[s][k] = (s < ns && c < HIDD) ? H[(size_t)(start + s) * HSTR + c] : 0.f;
        }

    float logit[8];
    #pragma unroll
    for (int s = 0; s < 8; ++s) {
        float t = q[0] * h[s][0] + q[1] * h[s][1] + q[2] * h[s][2] + q[3] * h[s][3];
        #pragma unroll
        for (int off = 32; off > 0; off >>= 1) t += __shfl_xor(t, off);
        logit[s] = t;   // all lanes hold it
    }

    float mx = -1e30f;
    for (int s = 0; s < ns; ++s) mx = fmaxf(mx, logit[s]);
    float a[8], den = 0.f;
    #pragma unroll
    for (int s = 0; s < 8; ++s) { a[s] = (s < ns) ? expf(logit[s] - mx) : 0.f; den += a[s]; }
    float inv = 1.f / den;

    float rep[4];
    #pragma unroll
    for (int k = 0; k < 4; ++k) {
        float r = 0.f;
        #pragma unroll
        for (int s = 0; s < 8; ++s) r += a[s] * h[s][k];
        rep[k] = r * inv;
    }

    // classifier: 25 rows of rel_w, coalesced wave reads (L2-broadcast)
    #pragma unroll 5
    for (int g = 0; g < NREL; ++g) {
        float t = 0.f;
        #pragma unroll
        for (int k = 0; k < 4; ++k) {
            int c = lane + 64 * k;
            t += (c < HIDD) ? rel_w[g * HIDD + c] * rep[k] : 0.f;
        }
        #pragma unroll
        for (int off = 32; off > 0; off >>= 1) t += __shfl_xor(t, off);
        if (lane == 0) out[b * NREL + g] = t + rel_b[g];
    }
}

extern "C" void kernel_launch(void* const* d_in, const int* in_sizes, int n_in,
                              void* d_out, int out_size, void* d_ws, size_t ws_size,
                              hipStream_t stream) {
    const int*   X        = (const int*)d_in[0];
    const int*   P1       = (const int*)d_in[1];
    const int*   P2       = (const int*)d_in[2];
    const int*   scope    = (const int*)d_in[5];
    const int*   relation = (const int*)d_in[6];
    const float* wemb     = (const float*)d_in[7];
    const float* p1emb    = (const float*)d_in[8];
    const float* p2emb    = (const float*)d_in[9];
    const float* conv_w   = (const float*)d_in[10];
    const float* conv_b   = (const float*)d_in[11];
    const float* rel_w    = (const float*)d_in[12];
    const float* rel_b    = (const float*)d_in[13];

    // workspace layout
    char* ws = (char*)d_ws;
    float* H = (float*)ws;                                   // 4000*232*4 = 3,712,000
    size_t off = (size_t)NSENT * HSTR * 4;
    unsigned short* Bfrag = (unsigned short*)(ws + off);     // 16*6*64*8*2 = 98,304

    const int btot = NTILEP * KSTEPS * 64 * 8;
    hipLaunchKernelGGL(prep_b, dim3((btot + 255) / 256), dim3(256), 0, stream,
                       conv_w, Bfrag);
    hipLaunchKernelGGL(encoder, dim3(NSENT), dim3(512), 0, stream,
                       X, P1, P2, wemb, p1emb, p2emb, Bfrag, conv_b, H);
    hipLaunchKernelGGL(attn, dim3(NBAG), dim3(64), 0, stream,
                       H, rel_w, rel_b, relation, scope, (float*)d_out);
}